// Round 1
// baseline (46.074 us; speedup 1.0000x reference)
//
#include <hip/hip_runtime.h>

#define WAVE 64

__global__ void hist_kernel(const int* __restrict__ targets, int n, int* __restrict__ cnt) {
    int i = blockIdx.x * blockDim.x + threadIdx.x;
    if (i < n) atomicAdd(&cnt[targets[i]], 1);
}

// S[d] = sum_i w[targets[i]][d]; rows split across gridDim.y, float atomicAdd into S
__global__ void ssum_kernel(const float* __restrict__ w, const int* __restrict__ targets,
                            int n, int D, float* __restrict__ S) {
    int d = blockIdx.x * blockDim.x + threadIdx.x;
    if (d >= D) return;
    int rows_per = (n + gridDim.y - 1) / gridDim.y;
    int r0 = blockIdx.y * rows_per;
    int r1 = min(r0 + rows_per, n);
    float acc = 0.f;
    for (int i = r0; i < r1; ++i) {
        int t = targets[i];
        acc += w[(size_t)t * D + d];
    }
    atomicAdd(&S[d], acc);
}

// One wave per row: dw = x_i . w[t_i], ds = x_i . S
// term_i = 1 - dw + (ds - c_i*dw) / (n - c_i); block-level partial sums.
__global__ void row_kernel(const float* __restrict__ x, const int* __restrict__ targets,
                           const float* __restrict__ w, const float* __restrict__ S,
                           const int* __restrict__ cnt, int n, int D,
                           float* __restrict__ partials) {
    int wave = threadIdx.x >> 6;
    int lane = threadIdx.x & 63;
    int row  = blockIdx.x * (blockDim.x >> 6) + wave;
    __shared__ float sm[8];
    float term = 0.f;
    if (row < n) {
        int t = targets[row];
        const float4* xr = (const float4*)(x + (size_t)row * D);
        const float4* wr = (const float4*)(w + (size_t)t * D);
        const float4* Sr = (const float4*)S;
        float dw = 0.f, ds = 0.f;
        int nv = D >> 2;
        for (int k = lane; k < nv; k += WAVE) {
            float4 a = xr[k];
            float4 b = wr[k];
            float4 s = Sr[k];
            dw += a.x*b.x + a.y*b.y + a.z*b.z + a.w*b.w;
            ds += a.x*s.x + a.y*s.y + a.z*s.z + a.w*s.w;
        }
        #pragma unroll
        for (int off = 32; off; off >>= 1) {
            dw += __shfl_down(dw, off);
            ds += __shfl_down(ds, off);
        }
        if (lane == 0) {
            float c = (float)cnt[t];
            term = 1.f - dw + (ds - c * dw) / ((float)n - c);
        }
    }
    if (lane == 0) sm[wave] = term;
    __syncthreads();
    if (threadIdx.x == 0) {
        float p = 0.f;
        int nw = blockDim.x >> 6;
        for (int i = 0; i < nw; ++i) p += sm[i];
        partials[blockIdx.x] = p;
    }
}

__global__ void final_kernel(const float* __restrict__ partials, int nb, int n,
                             float* __restrict__ out) {
    double acc = 0.0;
    for (int i = threadIdx.x; i < nb; i += WAVE) acc += (double)partials[i];
    #pragma unroll
    for (int off = 32; off; off >>= 1) acc += __shfl_down(acc, off);
    if (threadIdx.x == 0) out[0] = (float)(acc / (double)n);
}

extern "C" void kernel_launch(void* const* d_in, const int* in_sizes, int n_in,
                              void* d_out, int out_size, void* d_ws, size_t ws_size,
                              hipStream_t stream) {
    const float* x       = (const float*)d_in[0];
    const int*   targets = (const int*)d_in[1];
    const float* w       = (const float*)d_in[2];

    int N = in_sizes[1];
    int D = in_sizes[0] / N;
    int C = in_sizes[2] / D;

    char* wsb = (char*)d_ws;
    size_t cnt_bytes = ((size_t)C * sizeof(int) + 255) & ~(size_t)255;
    size_t s_bytes   = ((size_t)D * sizeof(float) + 255) & ~(size_t)255;
    int* cnt        = (int*)wsb;
    float* S        = (float*)(wsb + cnt_bytes);
    float* partials = (float*)(wsb + cnt_bytes + s_bytes);

    hipMemsetAsync(cnt, 0, (size_t)C * sizeof(int), stream);
    hipMemsetAsync(S, 0, (size_t)D * sizeof(float), stream);

    hist_kernel<<<(N + 255) / 256, 256, 0, stream>>>(targets, N, cnt);

    dim3 g2((D + 255) / 256, 32);
    ssum_kernel<<<g2, 256, 0, stream>>>(w, targets, N, D, S);

    const int waves_per_block = 4;
    int nb = (N + waves_per_block - 1) / waves_per_block;
    row_kernel<<<nb, waves_per_block * WAVE, 0, stream>>>(x, targets, w, S, cnt, N, D, partials);

    final_kernel<<<1, WAVE, 0, stream>>>(partials, nb, N, (float*)d_out);
}